// Round 7
// baseline (273.104 us; speedup 1.0000x reference)
//
#include <hip/hip_runtime.h>
#include <math.h>

// EuclideanCodebook: x (8,4096,256) fp32, embed (8192,256) fp32
// out = embed[argmin_k ||x - e_k||^2], first-index tie rule.
//
// R12: R11 + two changes attacking the measured top consumer (LDS read pipe
// ~1800 of 3863 cyc/tile):
//  (1) wave decomposition 4rowg x 2colg -> 2rowg x 4colg (64 rows x 16 cols
//      per wave). B-slice read duplication = nrowg: 4 -> 2, halving ds_read
//      traffic (128 -> 64 b128/CU/tile) and bank conflicts. af grows to
//      af[4][8] = 128 VGPRs; total demand ~210 < 256 budget of
//      waves_per_eu(1,2) at 512 thr (R6/R9b-verified law: 512-thr = big
//      budget, VGPR_Count=128..256, no scratch).
//  (2) phase = 2 tiles: one vmcnt+raw-barrier per 128 codes (64 barriers vs
//      128). Issue-after-barrier, prefetch slack = 1 full phase (~2 tiles of
//      compute >> L2 latency), so vmcnt(0) is free in steady state; the
//      pair issued goes into the buffer pair read last phase (WAR safe).
// Selection widens to 64 streams x top-2 = 128 candidates/row (stride-129
// merge, conflict-free readers); exact fp32 recheck + gather unchanged
// (validated rounding sequence, absmax 0 through R11).

#define DIM 256
#define KCODES 8192
#define NROWS 32768
#define TILE_CODES 64
#define NT (KCODES / TILE_CODES)   // 128

typedef _Float16 half8 __attribute__((ext_vector_type(8)));
typedef _Float16 half4_t __attribute__((ext_vector_type(4)));
typedef float f32x4 __attribute__((ext_vector_type(4)));

// ---- ws layout (bytes) ----
#define ES_OFF 0u                 // 8192*256 f16 = 4194304
#define ESQ_OFF 4194304u          // 8192 f32     = 32768
#define WS_NEED 4227072u

#define GLOAD_LDS16(gp, lp) \
    __builtin_amdgcn_global_load_lds((const __attribute__((address_space(1))) void*)(gp), \
                                     (__attribute__((address_space(3))) void*)(lp), 16, 0, 0)

// ---------------- prep: embed fp32 -> fp16 + e_sq (approx use only) ----------------
__global__ void cvt_esq(const float* __restrict__ emb, _Float16* __restrict__ Es,
                        float* __restrict__ esq) {
    const int gid = blockIdx.x * 256 + threadIdx.x;
    const int code = gid >> 2, q = gid & 3;
    const float4* src = (const float4*)(emb + (size_t)code * DIM + q * 64);
    half4_t* dst = (half4_t*)(Es + (size_t)code * DIM + q * 64);
    float s = 0.f;
#pragma unroll
    for (int i = 0; i < 16; ++i) {
        const float4 v = src[i];
        half4_t h;
        h[0] = (_Float16)v.x; h[1] = (_Float16)v.y; h[2] = (_Float16)v.z; h[3] = (_Float16)v.w;
        dst[i] = h;
        s = fmaf(v.x, v.x, s); s = fmaf(v.y, v.y, s);
        s = fmaf(v.z, v.z, s); s = fmaf(v.w, v.w, s);
    }
    s += __shfl_xor(s, 1);
    s += __shfl_xor(s, 2);
    if (q == 0) esq[code] = s;
}

// ---------------- fused: MFMA score + top-4 + exact recheck + gather ----------------
// grid 256 blocks x 512 threads (8 waves). Block owns rows [blockIdx*128, +128).
// Wave wv: rowg = wv&1 (64-row slice), colg = wv>>1 (16-col slice of 64-code tile).
__global__ __attribute__((amdgpu_flat_work_group_size(512, 512)))
__attribute__((amdgpu_waves_per_eu(1, 2))) void vq_fused(
    const float* __restrict__ x, const _Float16* __restrict__ Es,
    const float* __restrict__ esq, const float* __restrict__ embed,
    float* __restrict__ out)
{
    __shared__ __align__(16) char arena[131072];   // 4 x 32 KB tile buffers + overlays

    const int tid = threadIdx.x;
    const int lane = tid & 63;
    const int wv = tid >> 6;        // 0..7
    const int rowg = wv & 1;        // 2 row groups x 64 rows
    const int colg = wv >> 1;       // 4 col groups x 16 cols
    const int lm = lane & 15;
    const int quad = lane >> 4;
    const int rowblk = blockIdx.x * 128;

    // post-K-loop overlays inside the arena (all uses after the post-loop barrier)
    float* mb = (float*)arena;                          // [128][129] f = 66048 B
    float (*top4s)[4] = (float (*)[4])(arena + 66560);  // 2048 B
    float (*rd)[4] = (float (*)[4])(arena + 68608);     // 2048 B
    int (*rk)[4] = (int (*)[4])(arena + 70656);         // 2048 B
    int* win = (int*)(arena + 72704);                   // 512 B

    // staging role: wave stages codes [wv*8, wv*8+8) of each tile (4 x 1KB loads)
    const int bpos = lane & 31;
    const int cl_lo = wv * 8 + (lane >> 5);
    const _Float16* g0 = Es + (size_t)(cl_lo + 0) * 256 + (size_t)((bpos ^ ((cl_lo + 0) & 7)) * 8);
    const _Float16* g1 = Es + (size_t)(cl_lo + 2) * 256 + (size_t)((bpos ^ ((cl_lo + 2) & 7)) * 8);
    const _Float16* g2 = Es + (size_t)(cl_lo + 4) * 256 + (size_t)((bpos ^ ((cl_lo + 4) & 7)) * 8);
    const _Float16* g3 = Es + (size_t)(cl_lo + 6) * 256 + (size_t)((bpos ^ ((cl_lo + 6) & 7)) * 8);

    float ea0, eb0, ea1, eb1;

    // packet = PAIR of tiles: 8 global_load_lds + 2 esq loads
#define ISSUE_PAIR(TP, BQ0, BQ1, EA, EB) do {                                 \
        char* d0_ = arena + (BQ0) * 32768;                                    \
        GLOAD_LDS16(g0, d0_ + (wv * 8 + 0) * 512);                            \
        GLOAD_LDS16(g1, d0_ + (wv * 8 + 2) * 512);                            \
        GLOAD_LDS16(g2, d0_ + (wv * 8 + 4) * 512);                            \
        GLOAD_LDS16(g3, d0_ + (wv * 8 + 6) * 512);                            \
        g0 += TILE_CODES * 256; g1 += TILE_CODES * 256;                       \
        g2 += TILE_CODES * 256; g3 += TILE_CODES * 256;                       \
        char* d1_ = arena + (BQ1) * 32768;                                    \
        GLOAD_LDS16(g0, d1_ + (wv * 8 + 0) * 512);                            \
        GLOAD_LDS16(g1, d1_ + (wv * 8 + 2) * 512);                            \
        GLOAD_LDS16(g2, d1_ + (wv * 8 + 4) * 512);                            \
        GLOAD_LDS16(g3, d1_ + (wv * 8 + 6) * 512);                            \
        g0 += TILE_CODES * 256; g1 += TILE_CODES * 256;                       \
        g2 += TILE_CODES * 256; g3 += TILE_CODES * 256;                       \
        const float* ep_ = esq + (size_t)(TP) * 128 + colg * 16 + lm;         \
        EA = ep_[0]; EB = ep_[64];                                            \
    } while (0)

    // one tile: 8 ds_read_b128 (one per ks), 4 MFMA each; 16-slot top-2 epilogue
#define COMPUTE_TILE(TT, Q, ER) do {                                                     \
        f32x4 a0_, a1_, a2_, a3_;                                                        \
        { const float v_ = -0.5f * (ER);                                                 \
          const f32x4 iv_ = {v_, v_, v_, v_};                                            \
          a0_ = iv_; a1_ = iv_; a2_ = iv_; a3_ = iv_; }                                  \
        const _Float16* Bq_ = (const _Float16*)(arena + (Q) * 32768);                    \
        const int cb_ = (colg * 16 + lm) * 256;                                          \
        _Pragma("unroll")                                                                \
        for (int ks = 0; ks < 8; ++ks) {                                                 \
            const int sw_ = ((ks * 4 + quad) ^ (lm & 7)) * 8;                            \
            const half8 bf_ = *(const half8*)(&Bq_[cb_ + sw_]);                          \
            a0_ = __builtin_amdgcn_mfma_f32_16x16x32_f16(af[0][ks], bf_, a0_, 0, 0, 0);  \
            a1_ = __builtin_amdgcn_mfma_f32_16x16x32_f16(af[1][ks], bf_, a1_, 0, 0, 0);  \
            a2_ = __builtin_amdgcn_mfma_f32_16x16x32_f16(af[2][ks], bf_, a2_, 0, 0, 0);  \
            a3_ = __builtin_amdgcn_mfma_f32_16x16x32_f16(af[3][ks], bf_, a3_, 0, 0, 0);  \
        }                                                                                \
        const unsigned kk_ = (unsigned)((TT) * TILE_CODES + colg * 16 + lm);             \
        _Pragma("unroll")                                                                \
        for (int r = 0; r < 4; ++r) {                                                    \
            { const float pv = __uint_as_float((__float_as_uint(a0_[r]) & 0xFFFFE000u) | kk_); \
              p2[r] = __builtin_amdgcn_fmed3f(p1[r], p2[r], pv); p1[r] = fmaxf(p1[r], pv); }   \
            { const float pv = __uint_as_float((__float_as_uint(a1_[r]) & 0xFFFFE000u) | kk_); \
              p2[4+r] = __builtin_amdgcn_fmed3f(p1[4+r], p2[4+r], pv); p1[4+r] = fmaxf(p1[4+r], pv); } \
            { const float pv = __uint_as_float((__float_as_uint(a2_[r]) & 0xFFFFE000u) | kk_); \
              p2[8+r] = __builtin_amdgcn_fmed3f(p1[8+r], p2[8+r], pv); p1[8+r] = fmaxf(p1[8+r], pv); } \
            { const float pv = __uint_as_float((__float_as_uint(a3_[r]) & 0xFFFFE000u) | kk_); \
              p2[12+r] = __builtin_amdgcn_fmed3f(p1[12+r], p2[12+r], pv); p1[12+r] = fmaxf(p1[12+r], pv); } \
        }                                                                                \
    } while (0)

    // issue pair 0 FIRST so its latency hides under the A-fragment load phase
    ISSUE_PAIR(0, 0, 1, ea0, eb0);

    // ---- A fragments register-resident (fp32 x -> fp16): 64 rows -> 128 VGPRs ----
    half8 af[4][8];
#pragma unroll
    for (int am = 0; am < 4; ++am) {
        const float* xr = x + (size_t)(rowblk + rowg * 64 + am * 16 + lm) * DIM + quad * 8;
#pragma unroll
        for (int ks = 0; ks < 8; ++ks) {
            const float4 a = *(const float4*)(xr + ks * 32);
            const float4 b = *(const float4*)(xr + ks * 32 + 4);
            half8 h;
            h[0] = (_Float16)a.x; h[1] = (_Float16)a.y; h[2] = (_Float16)a.z; h[3] = (_Float16)a.w;
            h[4] = (_Float16)b.x; h[5] = (_Float16)b.y; h[6] = (_Float16)b.z; h[7] = (_Float16)b.w;
            af[am][ks] = h;
        }
    }

    // packed (score | index in low 13 mantissa bits) top-2 per row-slot (16 slots)
    float p1[16], p2[16];
#pragma unroll
    for (int i = 0; i < 16; ++i) { p1[i] = -INFINITY; p2[i] = -INFINITY; }

    // main loop: 2 phases per iter, 2 tiles per phase. vmcnt(0) is free in
    // steady state (waited packet was issued one full phase earlier).
    for (int T = 0; T < 62; T += 2) {
        asm volatile("s_waitcnt vmcnt(0)" ::: "memory");
        __builtin_amdgcn_s_barrier();
        ISSUE_PAIR(T + 1, 2, 3, ea1, eb1);
        COMPUTE_TILE(2 * T + 0, 0, ea0);
        COMPUTE_TILE(2 * T + 1, 1, eb0);
        asm volatile("s_waitcnt vmcnt(0)" ::: "memory");
        __builtin_amdgcn_s_barrier();
        ISSUE_PAIR(T + 2, 0, 1, ea0, eb0);
        COMPUTE_TILE(2 * T + 2, 2, ea1);
        COMPUTE_TILE(2 * T + 3, 3, eb1);
    }
    // peel: pairs 62, 63
    asm volatile("s_waitcnt vmcnt(0)" ::: "memory");
    __builtin_amdgcn_s_barrier();
    ISSUE_PAIR(63, 2, 3, ea1, eb1);
    COMPUTE_TILE(124, 0, ea0);
    COMPUTE_TILE(125, 1, eb0);
    asm volatile("s_waitcnt vmcnt(0)" ::: "memory");
    __builtin_amdgcn_s_barrier();
    COMPUTE_TILE(126, 2, ea1);
    COMPUTE_TILE(127, 3, eb1);

    __syncthreads();   // full drain once; arena becomes merge scratch

    // ---- merge: per row, 64 streams x top-2 = 128 packed values -> top-4 ----
    // stride 129 floats: reader banks = (tid*129+p)%32 = (tid+p)%32 -> conflict-free
#pragma unroll
    for (int s = 0; s < 16; ++s) {
        const int row = rowg * 64 + (s >> 2) * 16 + quad * 4 + (s & 3);
        const int pos = (colg * 16 + lm) * 2;
        mb[row * 129 + pos] = p1[s];
        mb[row * 129 + pos + 1] = p2[s];
    }
    __syncthreads();
    if (tid < 128) {
        float t1 = -INFINITY, t2 = -INFINITY, t3 = -INFINITY, t4 = -INFINITY;
        for (int p = 0; p < 128; ++p) {
            const float v = mb[tid * 129 + p];
            const float m1 = fminf(t1, v);
            t1 = fmaxf(t1, v);
            const float m2 = fminf(t2, m1);
            t2 = fmaxf(t2, m1);
            const float m3 = fminf(t3, m2);
            t3 = fmaxf(t3, m2);
            t4 = fmaxf(t4, m3);
        }
        top4s[tid][0] = t1; top4s[tid][1] = t2; top4s[tid][2] = t3; top4s[tid][3] = t4;
    }
    __syncthreads();

    // ---- exact fp32 recheck: 4 threads/row, 1 candidate each ----
    {
        const int row = tid >> 2;
        const int ci = tid & 3;
        const int k = (int)(__float_as_uint(top4s[row][ci]) & 8191u);
        const float4* x4 = (const float4*)(x + (size_t)(rowblk + row) * DIM);
        float cs[4];
#pragma unroll
        for (int co = 0; co < 4; ++co) {
            float s = 0.f;
            for (int c4 = 0; c4 < 16; ++c4) {
                const float4 v = x4[co * 16 + c4];
                s = fmaf(v.x, v.x, s); s = fmaf(v.y, v.y, s);
                s = fmaf(v.z, v.z, s); s = fmaf(v.w, v.w, s);
            }
            cs[co] = s;
        }
        const float xsq = ((cs[0] + cs[1]) + cs[2]) + cs[3];
        const float4* e4 = (const float4*)(embed + (size_t)k * DIM);
        float dot = 0.f, es = 0.f;
        for (int c4 = 0; c4 < 64; ++c4) {
            const float4 xv = x4[c4], evv = e4[c4];
            dot = fmaf(xv.x, evv.x, dot); dot = fmaf(xv.y, evv.y, dot);
            dot = fmaf(xv.z, evv.z, dot); dot = fmaf(xv.w, evv.w, dot);
            es = fmaf(evv.x, evv.x, es); es = fmaf(evv.y, evv.y, es);
            es = fmaf(evv.z, evv.z, es); es = fmaf(evv.w, evv.w, es);
        }
        rd[row][ci] = fmaf(-2.0f, dot, xsq) + es;   // validated rounding sequence
        rk[row][ci] = k;
    }
    __syncthreads();
    if (tid < 128) {
        float best = rd[tid][0]; int bidx = rk[tid][0];
#pragma unroll
        for (int t = 1; t < 4; ++t) {
            const float d2 = rd[tid][t]; const int k2 = rk[tid][t];
            if (d2 < best || (d2 == best && k2 < bidx)) { best = d2; bidx = k2; }
        }
        win[tid] = bidx;
    }
    __syncthreads();

    // ---- coalesced gather ----
    {
        const int q = tid & 63;
        const int rb = tid >> 6;
        const float4* e4 = (const float4*)embed;
        float4* o4 = (float4*)out;
#pragma unroll
        for (int p = 0; p < 16; ++p) {
            const int r = rb + p * 8;
            const int k = win[r];
            o4[(size_t)(rowblk + r) * 64 + q] = e4[(size_t)k * 64 + q];
        }
    }
#undef COMPUTE_TILE
#undef ISSUE_PAIR
}

// ---------------- Fallback (round-1 kernel, passed absmax 0) ----------------
#define BM 64
#define BN 128
#define BC 64
#define NKT (KCODES / BN)
#define NCC (DIM / BC)

__global__ __launch_bounds__(256, 3) void vq_argmin_gather(
    const float* __restrict__ x, const float* __restrict__ embed,
    float* __restrict__ out)
{
    __shared__ __align__(16) float xs[BC * BM];
    __shared__ __align__(16) float es[BC * BN];
    const int tid = threadIdx.x;
    const int tx = tid & 15;
    const int ty = tid >> 4;
    const int row0 = blockIdx.x * BM;
    float xsq[4];
    {
        const int m = tid >> 2;
        const int quarter = tid & 3;
        const float* xr = x + (size_t)(row0 + m) * DIM + quarter * 64;
        float s = 0.f;
        for (int c = 0; c < 64; ++c) s = fmaf(xr[c], xr[c], s);
        es[tid] = s;
        __syncthreads();
#pragma unroll
        for (int i = 0; i < 4; ++i) {
            const int r = 4 * ty + i;
            xsq[i] = ((es[4*r] + es[4*r+1]) + es[4*r+2]) + es[4*r+3];
        }
        __syncthreads();
    }
    float bd[4] = {INFINITY, INFINITY, INFINITY, INFINITY};
    int bk[4] = {0, 0, 0, 0};
    for (int kt = 0; kt < NKT; ++kt) {
        const int k0 = kt * BN;
        float acc[4][8];
#pragma unroll
        for (int i = 0; i < 4; ++i)
#pragma unroll
            for (int j = 0; j < 8; ++j) acc[i][j] = 0.f;
        float e_acc = 0.f;
        for (int cc = 0; cc < NCC; ++cc) {
            __syncthreads();
            {
                const int q = tid & 15;
                const int nb = tid >> 4;
#pragma unroll
                for (int p = 0; p < 4; ++p) {
                    const int m = nb + 16 * p;
                    const float4 v = *(const float4*)(x + (size_t)(row0 + m) * DIM + cc * BC + 4 * q);
                    xs[(4*q+0)*BM+m] = v.x; xs[(4*q+1)*BM+m] = v.y;
                    xs[(4*q+2)*BM+m] = v.z; xs[(4*q+3)*BM+m] = v.w;
                }
#pragma unroll
                for (int p = 0; p < 8; ++p) {
                    const int n = nb + 16 * p;
                    const float4 v = *(const float4*)(embed + (size_t)(k0 + n) * DIM + cc * BC + 4 * q);
                    es[(4*q+0)*BN+n] = v.x; es[(4*q+1)*BN+n] = v.y;
                    es[(4*q+2)*BN+n] = v.z; es[(4*q+3)*BN+n] = v.w;
                }
            }
            __syncthreads();
            if (tid < BN) {
#pragma unroll 8
                for (int c = 0; c < BC; ++c) { const float v = es[c*BN+tid]; e_acc = fmaf(v, v, e_acc); }
            }
#pragma unroll 8
            for (int c = 0; c < BC; ++c) {
                const float4 a0 = *(const float4*)&xs[c*BM+4*ty];
                const float4 b0 = *(const float4*)&es[c*BN+4*tx];
                const float4 b1 = *(const float4*)&es[c*BN+64+4*tx];
                const float a[4] = {a0.x, a0.y, a0.z, a0.w};
                const float b[8] = {b0.x, b0.y, b0.z, b0.w, b1.x, b1.y, b1.z, b1.w};
#pragma unroll
                for (int i = 0; i < 4; ++i)
#pragma unroll
                    for (int j = 0; j < 8; ++j) acc[i][j] = fmaf(a[i], b[j], acc[i][j]);
            }
        }
        __syncthreads();
        if (tid < BN) es[tid] = e_acc;
        __syncthreads();
        float esq2[8];
#pragma unroll
        for (int j = 0; j < 4; ++j) { esq2[j] = es[4*tx+j]; esq2[4+j] = es[64+4*tx+j]; }
#pragma unroll
        for (int i = 0; i < 4; ++i)
#pragma unroll
            for (int j = 0; j < 8; ++j) {
                const float d = fmaf(-2.0f, acc[i][j], xsq[i]) + esq2[j];
                const int kk = k0 + ((j < 4) ? (4*tx+j) : (64+4*tx+(j-4)));
                if (d < bd[i]) { bd[i] = d; bk[i] = kk; }
            }
    }
    __syncthreads();
    float* red_d = xs;
    int* red_k = (int*)es;
#pragma unroll
    for (int i = 0; i < 4; ++i) { const int r = 4*ty+i; red_d[r*16+tx] = bd[i]; red_k[r*16+tx] = bk[i]; }
    __syncthreads();
    int winner = 0;
    if (tid < BM) {
        float best = red_d[tid*16]; int bidx = red_k[tid*16];
#pragma unroll
        for (int t = 1; t < 16; ++t) {
            const float d2 = red_d[tid*16+t]; const int k2 = red_k[tid*16+t];
            if (d2 < best || (d2 == best && k2 < bidx)) { best = d2; bidx = k2; }
        }
        winner = bidx;
    }
    __syncthreads();
    int* wn = (int*)xs;
    if (tid < BM) wn[tid] = winner;
    __syncthreads();
    {
        const int q = tid & 63;
        const int rb = tid >> 6;
        const float4* e4 = (const float4*)embed;
        float4* o4 = (float4*)out;
#pragma unroll
        for (int p = 0; p < 16; ++p) {
            const int rr = rb + 4 * p;
            const int k = wn[rr];
            o4[(size_t)(row0 + rr) * 64 + q] = e4[(size_t)k * 64 + q];
        }
    }
}

extern "C" void kernel_launch(void* const* d_in, const int* in_sizes, int n_in,
                              void* d_out, int out_size, void* d_ws, size_t ws_size,
                              hipStream_t stream) {
    const float* x = (const float*)d_in[0];
    const float* embed = (const float*)d_in[1];
    float* out = (float*)d_out;

    if (ws_size < (size_t)WS_NEED) {
        hipLaunchKernelGGL(vq_argmin_gather, dim3(NROWS / BM), dim3(256), 0, stream, x, embed, out);
        return;
    }
    char* ws = (char*)d_ws;
    _Float16* Es = (_Float16*)(ws + ES_OFF);
    float* esq = (float*)(ws + ESQ_OFF);

    hipLaunchKernelGGL(cvt_esq, dim3(128), dim3(256), 0, stream, embed, Es, esq);
    hipLaunchKernelGGL(vq_fused, dim3(256), dim3(512), 0, stream, x, Es, esq, embed, out);
}